// Round 2
// baseline (231.912 us; speedup 1.0000x reference)
//
#include <hip/hip_runtime.h>

#define ROW_LEN 2048
#define WAVES_PER_BLOCK 4
#define BLOCK (WAVES_PER_BLOCK * 64)
#define V4_PER_LANE (ROW_LEN / 4 / 64)   // 8 float4 per lane
#define EPS 1e-5f

typedef float vf4 __attribute__((ext_vector_type(4)));

__global__ __launch_bounds__(BLOCK) void RMSNorm_56607668961691_kernel(
    const vf4* __restrict__ x,
    const vf4* __restrict__ g,
    vf4* __restrict__ out,
    int rows)
{
    const int wave = threadIdx.x >> 6;
    const int lane = threadIdx.x & 63;
    const int row  = blockIdx.x * WAVES_PER_BLOCK + wave;
    if (row >= rows) return;

    const vf4* __restrict__ xr   = x   + (size_t)row * (ROW_LEN / 4);
    vf4* __restrict__       outr = out + (size_t)row * (ROW_LEN / 4);

    // 8 independent 16B loads per lane, coalesced: lane i touches bytes
    // [i*16 + k*1024), k=0..7 — contiguous 1 KiB per wave per k.
    vf4 v[V4_PER_LANE];
    #pragma unroll
    for (int k = 0; k < V4_PER_LANE; ++k)
        v[k] = xr[lane + k * 64];

    float ss = 0.0f;
    #pragma unroll
    for (int k = 0; k < V4_PER_LANE; ++k)
        ss += v[k].x * v[k].x + v[k].y * v[k].y + v[k].z * v[k].z + v[k].w * v[k].w;

    // 64-lane butterfly: every lane ends with the full row sum. No LDS, no barrier.
    #pragma unroll
    for (int off = 32; off > 0; off >>= 1)
        ss += __shfl_xor(ss, off, 64);

    const float scale = rsqrtf(ss * (1.0f / (float)ROW_LEN) + EPS);

    // g is 8 KiB total — L1-resident after first wave touches it.
    #pragma unroll
    for (int k = 0; k < V4_PER_LANE; ++k) {
        vf4 gk = g[lane + k * 64];
        vf4 o;
        o.x = v[k].x * scale * gk.x;
        o.y = v[k].y * scale * gk.y;
        o.z = v[k].z * scale * gk.z;
        o.w = v[k].w * scale * gk.w;
        // non-temporal: mark output lines evict-first so they don't evict x from L3
        __builtin_nontemporal_store(o, &outr[lane + k * 64]);
    }
}

extern "C" void kernel_launch(void* const* d_in, const int* in_sizes, int n_in,
                              void* d_out, int out_size, void* d_ws, size_t ws_size,
                              hipStream_t stream) {
    const vf4* x = (const vf4*)d_in[0];
    const vf4* g = (const vf4*)d_in[1];
    vf4* out = (vf4*)d_out;

    const int rows = in_sizes[0] / ROW_LEN;                 // 16384
    const int grid = (rows + WAVES_PER_BLOCK - 1) / WAVES_PER_BLOCK;
    RMSNorm_56607668961691_kernel<<<grid, BLOCK, 0, stream>>>(x, g, out, rows);
}